// Round 10
// baseline (206.998 us; speedup 1.0000x reference)
//
#include <hip/hip_runtime.h>
#include <math.h>

typedef unsigned long long ull;
typedef __attribute__((ext_vector_type(8))) short bf16x8;
typedef __attribute__((ext_vector_type(4))) float f32x4;

#define PPB   16384
#define NB    4
#define TOPK  4096
#define NPTS  65536
#define NBUCK 16384

// workspace layout (bytes)
#define SRAW_OFF  0u          // N f32 (256 KB)
#define ST_OFF    262144u     // 64 words stats
#define SUF_OFF   262400u     // 4*16384 u32 (256 KB)
#define CAND_OFF  524544u     // 4*16384 u64 (512 KB)
#define FIDX_OFF  1048832u    // 16384 i32
#define SW_OFF    1114368u    // 16384 f32
#define W2SH_OFF  1179904u    // 256*256 bf16 chunk-swizzled image (hi)
#define W2SL_OFF  1310976u    // (lo)
#define WP1H_OFF  1442048u    // wp1^T image (hi)
#define WP1L_OFF  1573120u    // (lo)   end 1704192

// stats word indices
#define SI_SUMS  0
#define SI_SUMS2 1
#define SI_ESEL  12  // ..15 per-batch sum exp (selected)

union frag_u { unsigned d[4]; bf16x8 v; uint4 q; };

__device__ __forceinline__ unsigned short f2bf(float f) {
  unsigned u = __float_as_uint(f);
  unsigned r = 0x7FFFu + ((u >> 16) & 1u);   // RTNE
  return (unsigned short)((u + r) >> 16);
}
__device__ __forceinline__ float bf2f(unsigned short h) {
  return __uint_as_float((unsigned)h << 16);
}

// ---------------- prep: images (coalesced) + stats zeroing ----------------
__global__ __launch_bounds__(256) void k_prep(
    const float* __restrict__ w2, const float* __restrict__ wp1,
    unsigned short* __restrict__ w2h, unsigned short* __restrict__ w2l,
    unsigned short* __restrict__ p1h, unsigned short* __restrict__ p1l,
    float* __restrict__ stats)
{
  const int t = threadIdx.x, bx = blockIdx.x;
  if (bx >= 16) {
    if (t < 64) stats[t] = 0.f;
    return;
  }
  __shared__ unsigned short lh[8192], ll[8192];
  const int c = bx & 7;
  const float* src = (bx >= 8) ? wp1 : w2;
  unsigned short* dh = (bx >= 8) ? p1h : w2h;
  unsigned short* dl = (bx >= 8) ? p1l : w2l;
  const int sw = (t >> 1) & 3;
#pragma unroll
  for (int kk = 0; kk < 32; ++kk) {
    float v = src[(c * 32 + kk) * 256 + t];      // coalesced 256-wide
    unsigned short h = f2bf(v);
    int q = kk >> 3, kof = kk & 7;
    int off = t * 32 + ((q ^ sw) << 3) + kof;
    lh[off] = h;
    ll[off] = f2bf(v - bf2f(h));
  }
  __syncthreads();
#pragma unroll
  for (int u = 0; u < 4; ++u) {
    ((uint4*)&dh[c * 8192])[u * 256 + t] = ((const uint4*)lh)[u * 256 + t];
    ((uint4*)&dl[c * 8192])[u * 256 + t] = ((const uint4*)ll)[u * 256 + t];
  }
}

// ---------------- K1: score-only point MLP, M=32/block ----------------
// (256,2) cap; demand ~150 VGPR -> no spill, ~3 waves/SIMD resident.
__global__ __launch_bounds__(256, 2) void k_mlp(
    const float4* __restrict__ pts4, const float* __restrict__ w1,
    const float* __restrict__ b1,
    const unsigned short* __restrict__ w2h, const unsigned short* __restrict__ w2l,
    const float* __restrict__ b2, const float* __restrict__ wsv,
    const float* __restrict__ bs,
    float* __restrict__ s_raw, float* stats_f)
{
  __shared__ float w1_l[1024];
  __shared__ float b1_l[256];
  __shared__ float pts_l[128];
  __shared__ float spart[128];

  const int t = threadIdx.x;
  const int m0 = blockIdx.x * 32;
  const int wv = t >> 6, lane = t & 63, g = lane >> 4, c0 = lane & 15;

#pragma unroll
  for (int i = 0; i < 4; ++i) w1_l[i * 256 + t] = w1[i * 256 + t];
  b1_l[t] = b1[t];
  if (t < 32) ((float4*)pts_l)[t] = pts4[m0 + t];

  f32x4 acc[2][4];
#pragma unroll
  for (int i = 0; i < 2; ++i)
#pragma unroll
    for (int j = 0; j < 4; ++j) acc[i][j] = (f32x4){0.f, 0.f, 0.f, 0.f};
  __syncthreads();

  float4 pr[2];
#pragma unroll
  for (int mt = 0; mt < 2; ++mt) pr[mt] = ((const float4*)pts_l)[mt * 16 + c0];

  int boff[4];
#pragma unroll
  for (int nt = 0; nt < 4; ++nt) {
    int n = wv * 64 + nt * 16 + c0;
    boff[nt] = n * 32 + ((g ^ ((n >> 1) & 3)) << 3);
  }
  bf16x8 bh[4], bl[4];
#pragma unroll
  for (int nt = 0; nt < 4; ++nt) {
    bh[nt] = *(const bf16x8*)&w2h[boff[nt]];
    bl[nt] = *(const bf16x8*)&w2l[boff[nt]];
  }

  for (int c = 0; c < 8; ++c) {
    const int kb = c * 32 + g * 8;
    float wk0[8], wk1[8], wk2[8], wk3[8], bk[8];
    *(float4*)&wk0[0] = *(const float4*)&w1_l[kb];
    *(float4*)&wk0[4] = *(const float4*)&w1_l[kb + 4];
    *(float4*)&wk1[0] = *(const float4*)&w1_l[256 + kb];
    *(float4*)&wk1[4] = *(const float4*)&w1_l[256 + kb + 4];
    *(float4*)&wk2[0] = *(const float4*)&w1_l[512 + kb];
    *(float4*)&wk2[4] = *(const float4*)&w1_l[512 + kb + 4];
    *(float4*)&wk3[0] = *(const float4*)&w1_l[768 + kb];
    *(float4*)&wk3[4] = *(const float4*)&w1_l[768 + kb + 4];
    *(float4*)&bk[0] = *(const float4*)&b1_l[kb];
    *(float4*)&bk[4] = *(const float4*)&b1_l[kb + 4];

    bf16x8 ah[2], al[2];
#pragma unroll
    for (int mt = 0; mt < 2; ++mt) {
      float4 pv = pr[mt];
      frag_u uh, ul;
#pragma unroll
      for (int jp = 0; jp < 4; ++jp) {
        int j0 = 2 * jp, j1 = 2 * jp + 1;
        float h0 = fmaf(pv.w, wk3[j0], fmaf(pv.z, wk2[j0],
                   fmaf(pv.y, wk1[j0], fmaf(pv.x, wk0[j0], bk[j0]))));
        float h1 = fmaf(pv.w, wk3[j1], fmaf(pv.z, wk2[j1],
                   fmaf(pv.y, wk1[j1], fmaf(pv.x, wk0[j1], bk[j1]))));
        h0 = fmaxf(h0, 0.f); h1 = fmaxf(h1, 0.f);
        unsigned u0 = __float_as_uint(h0), u1 = __float_as_uint(h1);
        uh.d[jp] = (u0 >> 16) | (u1 & 0xFFFF0000u);
        float r0 = h0 - __uint_as_float(u0 & 0xFFFF0000u);
        float r1 = h1 - __uint_as_float(u1 & 0xFFFF0000u);
        ul.d[jp] = (__float_as_uint(r0) >> 16) | (__float_as_uint(r1) & 0xFFFF0000u);
      }
      ah[mt] = uh.v; al[mt] = ul.v;
    }
#pragma unroll
    for (int mt = 0; mt < 2; ++mt)
#pragma unroll
      for (int nt = 0; nt < 4; ++nt) {
        acc[mt][nt] = __builtin_amdgcn_mfma_f32_16x16x32_bf16(ah[mt], bh[nt], acc[mt][nt], 0, 0, 0);
        acc[mt][nt] = __builtin_amdgcn_mfma_f32_16x16x32_bf16(al[mt], bh[nt], acc[mt][nt], 0, 0, 0);
        acc[mt][nt] = __builtin_amdgcn_mfma_f32_16x16x32_bf16(ah[mt], bl[nt], acc[mt][nt], 0, 0, 0);
      }
    if (c < 7) {
#pragma unroll
      for (int nt = 0; nt < 4; ++nt) {
        bh[nt] = *(const bf16x8*)&w2h[(c + 1) * 8192 + boff[nt]];
        bl[nt] = *(const bf16x8*)&w2l[(c + 1) * 8192 + boff[nt]];
      }
    }
  }

  // ---- epilogue: s row-sums only ----
  float wsr[4], b2v[4];
#pragma unroll
  for (int nt = 0; nt < 4; ++nt) {
    int col = wv * 64 + nt * 16 + c0;
    wsr[nt] = wsv[col]; b2v[nt] = b2[col];
  }
#pragma unroll
  for (int mt = 0; mt < 2; ++mt) {
    float srow[4] = {0.f, 0.f, 0.f, 0.f};
#pragma unroll
    for (int nt = 0; nt < 4; ++nt) {
      f32x4 z = acc[mt][nt];
#pragma unroll
      for (int r = 0; r < 4; ++r)
        srow[r] = fmaf(fmaxf(z[r] + b2v[nt], 0.f), wsr[nt], srow[r]);
    }
#pragma unroll
    for (int r = 0; r < 4; ++r) {
#pragma unroll
      for (int off = 1; off <= 8; off <<= 1) srow[r] += __shfl_xor(srow[r], off);
      if (c0 == 0) spart[(mt * 16 + g * 4 + r) * 4 + wv] = srow[r];
    }
  }
  __syncthreads();
  if (t < 64) {
    float s = 0.f, s2 = 0.f;
    if (t < 32) {
      s = bs[0] + spart[t * 4] + spart[t * 4 + 1] + spart[t * 4 + 2] + spart[t * 4 + 3];
      s_raw[m0 + t] = s;
      s2 = s * s;
    }
#pragma unroll
    for (int off = 32; off >= 1; off >>= 1) {
      s += __shfl_down(s, off);
      s2 += __shfl_down(s2, off);
    }
    if (t == 0) {
      atomicAdd(&stats_f[SI_SUMS], s);
      atomicAdd(&stats_f[SI_SUMS2], s2);
    }
  }
}

// ---------------- K2: fused scores + LDS hist + scan + scatter + rank ----------------
__global__ __launch_bounds__(1024) void k_sel(
    const float* __restrict__ s_raw, float* stats_f,
    const float* __restrict__ gamma, const float* __restrict__ beta,
    unsigned* __restrict__ suf_g, ull* __restrict__ cand,
    int* __restrict__ flat_idx, float* __restrict__ sw_raw)
{
  __shared__ __align__(16) unsigned lh[NBUCK];      // 64 KB
  __shared__ unsigned wsum[16], wsuf[16];
  __shared__ unsigned sb_cut, sb_tot;
  __shared__ float esel_sh[16];
  const int batch = blockIdx.x, t = threadIdx.x;
  const int lane = t & 63, w = t >> 6;
  const float mu = stats_f[SI_SUMS] * (1.f / 65536.f);
  const float ex2 = stats_f[SI_SUMS2] * (1.f / 65536.f);
  const float istd = 1.f / sqrtf(ex2 - mu * mu + 1e-5f);
  const float gm = gamma[0], be = beta[0];
  if (t == 0) { sb_cut = 0u; sb_tot = PPB; }
#pragma unroll
  for (int j = 0; j < 16; ++j) lh[j * 1024 + t] = 0u;
  __syncthreads();
  float sc_loc[16];
#pragma unroll
  for (int j = 0; j < 16; ++j) {
    float sc = fmaxf((s_raw[batch * PPB + j * 1024 + t] - mu) * istd * gm + be, 0.f);
    sc_loc[j] = sc;
    unsigned bucket = __float_as_uint(sc) >> 17;
    if (bucket > NBUCK - 1u) bucket = NBUCK - 1u;
    if (bucket >= 1u) atomicAdd(&lh[bucket], 1u);
  }
  __syncthreads();
  unsigned hl[16]; unsigned ct = 0;
#pragma unroll
  for (int i = 0; i < 16; ++i) { hl[i] = lh[t * 16 + i]; ct += hl[i]; }
  unsigned x = ct;
#pragma unroll
  for (int off = 1; off <= 32; off <<= 1) {
    unsigned v = __shfl_down(x, off);
    if (lane + off < 64) x += v;
  }
  if (lane == 0) wsum[w] = x;
  __syncthreads();
  if (t < 16) {
    unsigned s = 0;
    for (int j = t + 1; j < 16; ++j) s += wsum[j];
    wsuf[t] = s;
  }
  __syncthreads();
  unsigned run = wsuf[w] + (x - ct);
  for (int i = 15; i >= 0; --i) {
    int b = t * 16 + i;
    unsigned h = hl[i];
    lh[b] = run;
    if (b >= 1 && run < TOPK && run + h >= TOPK) { sb_cut = (unsigned)b; sb_tot = run + h; }
    run += h;
  }
  if (t == 0 && run < TOPK) { sb_cut = 0u; sb_tot = PPB; }
  __syncthreads();
#pragma unroll
  for (int j = 0; j < 16; ++j) suf_g[batch * NBUCK + j * 1024 + t] = lh[j * 1024 + t];
  __syncthreads();
  const unsigned cut = sb_cut, tot = sb_tot;
#pragma unroll
  for (int j = 0; j < 16; ++j) {
    unsigned bits = __float_as_uint(sc_loc[j]);
    unsigned bucket = bits >> 17;
    if (bucket > NBUCK - 1u) bucket = NBUCK - 1u;
    if (bucket >= cut) {
      unsigned pos = atomicAdd(&lh[bucket], 1u);
      cand[batch * PPB + pos] =
          ((ull)bits << 32) | (ull)(~(unsigned)(batch * PPB + j * 1024 + t));
    }
  }
  __threadfence();
  __syncthreads();
  // cursors dead now — reuse lh's 64 KB as ull candidate cache for the rank scan
  ull* cl = (ull*)lh;
  const bool use_lds = (tot <= 8192u);
  if (use_lds)
    for (unsigned pos = t; pos < tot; pos += 1024) cl[pos] = cand[batch * PPB + pos];
  __syncthreads();
  const ull* seg = use_lds ? (const ull*)cl : &cand[batch * PPB];
  float esel = 0.f;
  for (int pos = t; pos < (int)tot; pos += 1024) {
    ull key = seg[pos];
    unsigned bits = (unsigned)(key >> 32);
    unsigned bucket = bits >> 17;
    unsigned s0 = suf_g[batch * NBUCK + bucket];
    unsigned s1 = (bucket >= 1u) ? suf_g[batch * NBUCK + bucket - 1] : tot;
    unsigned rank = s0;
    for (unsigned p = s0; p < s1; ++p) rank += (seg[p] > key);
    if (rank < TOPK) {
      float E = expf((__uint_as_float(bits) - 5.f) * 10.f);
      flat_idx[batch * TOPK + rank] = (int)(~(unsigned)key);
      sw_raw[batch * TOPK + rank] = E;
      esel += E;
    }
  }
#pragma unroll
  for (int off = 32; off >= 1; off >>= 1) esel += __shfl_down(esel, off);
  if (lane == 0) esel_sh[w] = esel;
  __syncthreads();
  if (t == 0) {
    float s = 0.f;
    for (int j = 0; j < 16; ++j) s += esel_sh[j];
    stats_f[SI_ESEL + batch] = s;
  }
}

// ---------------- K3: fused double-GEMM processor, M=32/block ----------------
__global__ __launch_bounds__(256, 2) void k_proc(
    const float4* __restrict__ pts4, const float* __restrict__ w1,
    const float* __restrict__ b1,
    const unsigned short* __restrict__ w2h, const unsigned short* __restrict__ w2l,
    const float* __restrict__ b2,
    const float* stats_f, const int* __restrict__ flat_idx,
    const float* __restrict__ sw_raw,
    const unsigned short* __restrict__ p1h, const unsigned short* __restrict__ p1l,
    const float* __restrict__ bp1,
    const float4* __restrict__ wp2_4, const float* __restrict__ bp2,
    float4* __restrict__ out4)
{
  __shared__ float w1_l[1024];
  __shared__ float b1_l[256];
  __shared__ int idx_t[32];
  __shared__ float sw_t[32];
  __shared__ __align__(16) short sf_s[8192];   // 16 KB: 8 slabs [32 x 32k] swizzled
  __shared__ float opart[4 * 32 * 4];

  const int t = threadIdx.x;
  const int m0 = blockIdx.x * 32;
  const int b = m0 >> 12;
  const int wv = t >> 6, lane = t & 63, g = lane >> 4, c0 = lane & 15;

#pragma unroll
  for (int i = 0; i < 4; ++i) w1_l[i * 256 + t] = w1[i * 256 + t];
  b1_l[t] = b1[t];
  if (t < 32) {
    idx_t[t] = flat_idx[m0 + t];
    sw_t[t] = sw_raw[m0 + t] / stats_f[SI_ESEL + b];
  }
  f32x4 acc[2][4];
#pragma unroll
  for (int i = 0; i < 2; ++i)
#pragma unroll
    for (int j = 0; j < 4; ++j) acc[i][j] = (f32x4){0.f, 0.f, 0.f, 0.f};
  __syncthreads();

  float4 pr[2];
#pragma unroll
  for (int mt = 0; mt < 2; ++mt) pr[mt] = pts4[idx_t[mt * 16 + c0]];
  float swr[2][4];
#pragma unroll
  for (int mt = 0; mt < 2; ++mt)
#pragma unroll
    for (int r = 0; r < 4; ++r) swr[mt][r] = sw_t[mt * 16 + g * 4 + r];

  int boff[4];
#pragma unroll
  for (int nt = 0; nt < 4; ++nt) {
    int n = wv * 64 + nt * 16 + c0;
    boff[nt] = n * 32 + ((g ^ ((n >> 1) & 3)) << 3);
  }

  // ===== GEMM1: z1 = h @ w2 (A = RTNE bf16 of h; B = w2 hi/lo 2-chain) =====
  bf16x8 bh[4], bl[4];
#pragma unroll
  for (int nt = 0; nt < 4; ++nt) {
    bh[nt] = *(const bf16x8*)&w2h[boff[nt]];
    bl[nt] = *(const bf16x8*)&w2l[boff[nt]];
  }
  for (int c = 0; c < 8; ++c) {
    const int kb = c * 32 + g * 8;
    float wk0[8], wk1[8], wk2[8], wk3[8], bk[8];
    *(float4*)&wk0[0] = *(const float4*)&w1_l[kb];
    *(float4*)&wk0[4] = *(const float4*)&w1_l[kb + 4];
    *(float4*)&wk1[0] = *(const float4*)&w1_l[256 + kb];
    *(float4*)&wk1[4] = *(const float4*)&w1_l[256 + kb + 4];
    *(float4*)&wk2[0] = *(const float4*)&w1_l[512 + kb];
    *(float4*)&wk2[4] = *(const float4*)&w1_l[512 + kb + 4];
    *(float4*)&wk3[0] = *(const float4*)&w1_l[768 + kb];
    *(float4*)&wk3[4] = *(const float4*)&w1_l[768 + kb + 4];
    *(float4*)&bk[0] = *(const float4*)&b1_l[kb];
    *(float4*)&bk[4] = *(const float4*)&b1_l[kb + 4];

    bf16x8 ah[2];
#pragma unroll
    for (int mt = 0; mt < 2; ++mt) {
      float4 pv = pr[mt];
      frag_u uh;
#pragma unroll
      for (int jp = 0; jp < 4; ++jp) {
        int j0 = 2 * jp, j1 = 2 * jp + 1;
        float h0 = fmaf(pv.w, wk3[j0], fmaf(pv.z, wk2[j0],
                   fmaf(pv.y, wk1[j0], fmaf(pv.x, wk0[j0], bk[j0]))));
        float h1 = fmaf(pv.w, wk3[j1], fmaf(pv.z, wk2[j1],
                   fmaf(pv.y, wk1[j1], fmaf(pv.x, wk0[j1], bk[j1]))));
        uh.d[jp] = (unsigned)f2bf(fmaxf(h0, 0.f)) |
                   ((unsigned)f2bf(fmaxf(h1, 0.f)) << 16);
      }
      ah[mt] = uh.v;
    }
#pragma unroll
    for (int mt = 0; mt < 2; ++mt)
#pragma unroll
      for (int nt = 0; nt < 4; ++nt) {
        acc[mt][nt] = __builtin_amdgcn_mfma_f32_16x16x32_bf16(ah[mt], bh[nt], acc[mt][nt], 0, 0, 0);
        acc[mt][nt] = __builtin_amdgcn_mfma_f32_16x16x32_bf16(ah[mt], bl[nt], acc[mt][nt], 0, 0, 0);
      }
    if (c < 7) {
#pragma unroll
      for (int nt = 0; nt < 4; ++nt) {
        bh[nt] = *(const bf16x8*)&w2h[(c + 1) * 8192 + boff[nt]];
        bl[nt] = *(const bf16x8*)&w2l[(c + 1) * 8192 + boff[nt]];
      }
    }
  }

  // ===== transform: sf = relu(z1 + b2) * sw  ->  LDS bf16, A-layout swizzle =====
  {
    float b2v[4];
#pragma unroll
    for (int nt = 0; nt < 4; ++nt) b2v[nt] = b2[wv * 64 + nt * 16 + c0];
#pragma unroll
    for (int mt = 0; mt < 2; ++mt)
#pragma unroll
      for (int nt = 0; nt < 4; ++nt) {
        int n = wv * 64 + nt * 16 + c0;
        int slab = n >> 5, qc = (n >> 3) & 3, kof = n & 7;
#pragma unroll
        for (int r = 0; r < 4; ++r) {
          int m = mt * 16 + g * 4 + r;
          float v = fmaxf(acc[mt][nt][r] + b2v[nt], 0.f) * swr[mt][r];
          sf_s[slab * 1024 + m * 32 + ((qc ^ ((m >> 1) & 3)) << 3) + kof] = f2bf(v);
        }
      }
  }
  __syncthreads();

  // ===== GEMM2: y = sf @ wp1 (A = sf bf16; B = wp1 hi/lo 2-chain) =====
#pragma unroll
  for (int i = 0; i < 2; ++i)
#pragma unroll
    for (int j = 0; j < 4; ++j) acc[i][j] = (f32x4){0.f, 0.f, 0.f, 0.f};
#pragma unroll
  for (int nt = 0; nt < 4; ++nt) {
    bh[nt] = *(const bf16x8*)&p1h[boff[nt]];
    bl[nt] = *(const bf16x8*)&p1l[boff[nt]];
  }
  for (int c = 0; c < 8; ++c) {
#pragma unroll
    for (int mt = 0; mt < 2; ++mt) {
      int m = mt * 16 + c0;
      bf16x8 af = *(const bf16x8*)&sf_s[c * 1024 + m * 32 + ((g ^ ((m >> 1) & 3)) << 3)];
#pragma unroll
      for (int nt = 0; nt < 4; ++nt) {
        acc[mt][nt] = __builtin_amdgcn_mfma_f32_16x16x32_bf16(af, bh[nt], acc[mt][nt], 0, 0, 0);
        acc[mt][nt] = __builtin_amdgcn_mfma_f32_16x16x32_bf16(af, bl[nt], acc[mt][nt], 0, 0, 0);
      }
    }
    if (c < 7) {
#pragma unroll
      for (int nt = 0; nt < 4; ++nt) {
        bh[nt] = *(const bf16x8*)&p1h[(c + 1) * 8192 + boff[nt]];
        bl[nt] = *(const bf16x8*)&p1l[(c + 1) * 8192 + boff[nt]];
      }
    }
  }

  // ===== epilogue: out = relu(y + bp1) @ wp2 + bp2 (sw already applied) =====
  float4 wq[4]; float bp1v[4];
#pragma unroll
  for (int nt = 0; nt < 4; ++nt) {
    int n = wv * 64 + nt * 16 + c0;
    wq[nt] = wp2_4[n]; bp1v[nt] = bp1[n];
  }
#pragma unroll
  for (int mt = 0; mt < 2; ++mt) {
#pragma unroll
    for (int r = 0; r < 4; ++r) {
      float4 o = {0.f, 0.f, 0.f, 0.f};
#pragma unroll
      for (int nt = 0; nt < 4; ++nt) {
        float y = fmaxf(acc[mt][nt][r] + bp1v[nt], 0.f);
        o.x = fmaf(y, wq[nt].x, o.x); o.y = fmaf(y, wq[nt].y, o.y);
        o.z = fmaf(y, wq[nt].z, o.z); o.w = fmaf(y, wq[nt].w, o.w);
      }
#pragma unroll
      for (int off = 1; off <= 8; off <<= 1) {
        o.x += __shfl_xor(o.x, off); o.y += __shfl_xor(o.y, off);
        o.z += __shfl_xor(o.z, off); o.w += __shfl_xor(o.w, off);
      }
      if (c0 == 0) *(float4*)&opart[(wv * 32 + mt * 16 + g * 4 + r) * 4] = o;
    }
  }
  __syncthreads();
  if (t < 32) {
    float4 bp2v = *(const float4*)bp2;
    float4 s0 = *(float4*)&opart[t * 4];
    float4 s1 = *(float4*)&opart[(32 + t) * 4];
    float4 s2 = *(float4*)&opart[(64 + t) * 4];
    float4 s3 = *(float4*)&opart[(96 + t) * 4];
    float4 r;
    r.x = s0.x + s1.x + s2.x + s3.x + bp2v.x;
    r.y = s0.y + s1.y + s2.y + s3.y + bp2v.y;
    r.z = s0.z + s1.z + s2.z + s3.z + bp2v.z;
    r.w = s0.w + s1.w + s2.w + s3.w + bp2v.w;
    out4[m0 + t] = r;
  }
}

extern "C" void kernel_launch(void* const* d_in, const int* in_sizes, int n_in,
                              void* d_out, int out_size, void* d_ws, size_t ws_size,
                              hipStream_t stream) {
  const float* pts   = (const float*)d_in[0];
  const float* w1    = (const float*)d_in[1];
  const float* b1    = (const float*)d_in[2];
  const float* w2    = (const float*)d_in[3];
  const float* b2    = (const float*)d_in[4];
  const float* wsv   = (const float*)d_in[5];
  const float* bs    = (const float*)d_in[6];
  const float* gamma = (const float*)d_in[7];
  const float* beta  = (const float*)d_in[8];
  const float* wp1   = (const float*)d_in[9];
  const float* bp1   = (const float*)d_in[10];
  const float* wp2   = (const float*)d_in[11];
  const float* bp2   = (const float*)d_in[12];

  char* wsb = (char*)d_ws;
  float*    s_raw   = (float*)(wsb + SRAW_OFF);
  float*    stats_f = (float*)(wsb + ST_OFF);
  unsigned* suf     = (unsigned*)(wsb + SUF_OFF);
  ull*      cand    = (ull*)(wsb + CAND_OFF);
  int*      flat_i  = (int*)(wsb + FIDX_OFF);
  float*    sw_raw  = (float*)(wsb + SW_OFF);
  unsigned short* w2h = (unsigned short*)(wsb + W2SH_OFF);
  unsigned short* w2l = (unsigned short*)(wsb + W2SL_OFF);
  unsigned short* p1h = (unsigned short*)(wsb + WP1H_OFF);
  unsigned short* p1l = (unsigned short*)(wsb + WP1L_OFF);

  hipLaunchKernelGGL(k_prep, dim3(17), dim3(256), 0, stream,
                     w2, wp1, w2h, w2l, p1h, p1l, stats_f);
  hipLaunchKernelGGL(k_mlp, dim3(2048), dim3(256), 0, stream,
                     (const float4*)pts, w1, b1, w2h, w2l, b2, wsv, bs,
                     s_raw, stats_f);
  hipLaunchKernelGGL(k_sel, dim3(NB), dim3(1024), 0, stream,
                     s_raw, stats_f, gamma, beta, suf, cand, flat_i, sw_raw);
  hipLaunchKernelGGL(k_proc, dim3(512), dim3(256), 0, stream,
                     (const float4*)pts, w1, b1, w2h, w2l, b2,
                     stats_f, flat_i, sw_raw, p1h, p1l, bp1,
                     (const float4*)wp2, bp2, (float4*)d_out);
}

// Round 12
// 188.857 us; speedup vs baseline: 1.0961x; 1.0961x over previous
//
#include <hip/hip_runtime.h>
#include <math.h>

typedef unsigned long long ull;
typedef __attribute__((ext_vector_type(8))) short bf16x8;
typedef __attribute__((ext_vector_type(4))) float f32x4;

#define PPB   16384
#define NB    4
#define TOPK  4096
#define NPTS  65536
#define NBUCK 16384

// workspace layout (bytes)
#define SRAW_OFF  0u          // N f32 (256 KB)
#define ST_OFF    262144u     // 64 words stats
#define SUF_OFF   262400u     // 4*16384 u32 (256 KB)
#define CAND_OFF  524544u     // 4*16384 u64 (512 KB)
#define FIDX_OFF  1048832u    // 16384 i32
#define SW_OFF    1114368u    // 16384 f32
#define W2SH_OFF  1179904u    // 256*256 bf16 chunk-swizzled image (hi)
#define W2SL_OFF  1310976u    // (lo)
#define WP1H_OFF  1442048u    // wp1^T image (hi)
#define WP1L_OFF  1573120u    // (lo)   end 1704192

// stats word indices
#define SI_SUMS  0
#define SI_SUMS2 1
#define SI_ESEL  12  // ..15 per-batch sum exp (selected)

union frag_u { unsigned d[4]; bf16x8 v; uint4 q; };

__device__ __forceinline__ unsigned short f2bf(float f) {
  unsigned u = __float_as_uint(f);
  unsigned r = 0x7FFFu + ((u >> 16) & 1u);   // RTNE
  return (unsigned short)((u + r) >> 16);
}
__device__ __forceinline__ float bf2f(unsigned short h) {
  return __uint_as_float((unsigned)h << 16);
}

// ---------------- prep: images (coalesced) + stats zeroing ----------------
__global__ __launch_bounds__(256) void k_prep(
    const float* __restrict__ w2, const float* __restrict__ wp1,
    unsigned short* __restrict__ w2h, unsigned short* __restrict__ w2l,
    unsigned short* __restrict__ p1h, unsigned short* __restrict__ p1l,
    float* __restrict__ stats)
{
  const int t = threadIdx.x, bx = blockIdx.x;
  if (bx >= 16) {
    if (t < 64) stats[t] = 0.f;
    return;
  }
  __shared__ unsigned short lh[8192], ll[8192];
  const int c = bx & 7;
  const float* src = (bx >= 8) ? wp1 : w2;
  unsigned short* dh = (bx >= 8) ? p1h : w2h;
  unsigned short* dl = (bx >= 8) ? p1l : w2l;
  const int sw = (t >> 1) & 3;
#pragma unroll
  for (int kk = 0; kk < 32; ++kk) {
    float v = src[(c * 32 + kk) * 256 + t];      // coalesced 256-wide
    unsigned short h = f2bf(v);
    int q = kk >> 3, kof = kk & 7;
    int off = t * 32 + ((q ^ sw) << 3) + kof;
    lh[off] = h;
    ll[off] = f2bf(v - bf2f(h));
  }
  __syncthreads();
#pragma unroll
  for (int u = 0; u < 4; ++u) {
    ((uint4*)&dh[c * 8192])[u * 256 + t] = ((const uint4*)lh)[u * 256 + t];
    ((uint4*)&dl[c * 8192])[u * 256 + t] = ((const uint4*)ll)[u * 256 + t];
  }
}

// ---------------- K1: score-only point MLP, M=64/block (best known: ~48us) ----------------
// (256,2) ONLY: VGPR demand ~150; tighter bounds spill to scratch (R4/R6/R8).
__global__ __launch_bounds__(256, 2) void k_mlp(
    const float4* __restrict__ pts4, const float* __restrict__ w1,
    const float* __restrict__ b1,
    const unsigned short* __restrict__ w2h, const unsigned short* __restrict__ w2l,
    const float* __restrict__ b2, const float* __restrict__ wsv,
    const float* __restrict__ bs,
    float* __restrict__ s_raw, float* stats_f)
{
  __shared__ float w1_l[1024];
  __shared__ float b1_l[256];
  __shared__ float pts_l[256];
  __shared__ float spart[256];

  const int t = threadIdx.x;
  const int m0 = blockIdx.x * 64;
  const int wv = t >> 6, lane = t & 63, g = lane >> 4, c0 = lane & 15;

#pragma unroll
  for (int i = 0; i < 4; ++i) w1_l[i * 256 + t] = w1[i * 256 + t];
  b1_l[t] = b1[t];
  if (t < 64) ((float4*)pts_l)[t] = pts4[m0 + t];

  f32x4 acc[4][4];
#pragma unroll
  for (int i = 0; i < 4; ++i)
#pragma unroll
    for (int j = 0; j < 4; ++j) acc[i][j] = (f32x4){0.f, 0.f, 0.f, 0.f};
  __syncthreads();

  float4 pr[4];
#pragma unroll
  for (int mt = 0; mt < 4; ++mt) pr[mt] = ((const float4*)pts_l)[mt * 16 + c0];

  int boff[4];
#pragma unroll
  for (int nt = 0; nt < 4; ++nt) {
    int n = wv * 64 + nt * 16 + c0;
    boff[nt] = n * 32 + ((g ^ ((n >> 1) & 3)) << 3);
  }
  bf16x8 bh[4], bl[4];
#pragma unroll
  for (int nt = 0; nt < 4; ++nt) {
    bh[nt] = *(const bf16x8*)&w2h[boff[nt]];
    bl[nt] = *(const bf16x8*)&w2l[boff[nt]];
  }

  for (int c = 0; c < 8; ++c) {
    const int kb = c * 32 + g * 8;
    float wk0[8], wk1[8], wk2[8], wk3[8], bk[8];
    *(float4*)&wk0[0] = *(const float4*)&w1_l[kb];
    *(float4*)&wk0[4] = *(const float4*)&w1_l[kb + 4];
    *(float4*)&wk1[0] = *(const float4*)&w1_l[256 + kb];
    *(float4*)&wk1[4] = *(const float4*)&w1_l[256 + kb + 4];
    *(float4*)&wk2[0] = *(const float4*)&w1_l[512 + kb];
    *(float4*)&wk2[4] = *(const float4*)&w1_l[512 + kb + 4];
    *(float4*)&wk3[0] = *(const float4*)&w1_l[768 + kb];
    *(float4*)&wk3[4] = *(const float4*)&w1_l[768 + kb + 4];
    *(float4*)&bk[0] = *(const float4*)&b1_l[kb];
    *(float4*)&bk[4] = *(const float4*)&b1_l[kb + 4];

    bf16x8 ah[4], al[4];
#pragma unroll
    for (int mt = 0; mt < 4; ++mt) {
      float4 pv = pr[mt];
      frag_u uh, ul;
#pragma unroll
      for (int jp = 0; jp < 4; ++jp) {
        int j0 = 2 * jp, j1 = 2 * jp + 1;
        float h0 = fmaf(pv.w, wk3[j0], fmaf(pv.z, wk2[j0],
                   fmaf(pv.y, wk1[j0], fmaf(pv.x, wk0[j0], bk[j0]))));
        float h1 = fmaf(pv.w, wk3[j1], fmaf(pv.z, wk2[j1],
                   fmaf(pv.y, wk1[j1], fmaf(pv.x, wk0[j1], bk[j1]))));
        h0 = fmaxf(h0, 0.f); h1 = fmaxf(h1, 0.f);
        unsigned u0 = __float_as_uint(h0), u1 = __float_as_uint(h1);
        uh.d[jp] = (u0 >> 16) | (u1 & 0xFFFF0000u);
        float r0 = h0 - __uint_as_float(u0 & 0xFFFF0000u);
        float r1 = h1 - __uint_as_float(u1 & 0xFFFF0000u);
        ul.d[jp] = (__float_as_uint(r0) >> 16) | (__float_as_uint(r1) & 0xFFFF0000u);
      }
      ah[mt] = uh.v; al[mt] = ul.v;
    }
#pragma unroll
    for (int mt = 0; mt < 4; ++mt)
#pragma unroll
      for (int nt = 0; nt < 4; ++nt) {
        acc[mt][nt] = __builtin_amdgcn_mfma_f32_16x16x32_bf16(ah[mt], bh[nt], acc[mt][nt], 0, 0, 0);
        acc[mt][nt] = __builtin_amdgcn_mfma_f32_16x16x32_bf16(al[mt], bh[nt], acc[mt][nt], 0, 0, 0);
        acc[mt][nt] = __builtin_amdgcn_mfma_f32_16x16x32_bf16(ah[mt], bl[nt], acc[mt][nt], 0, 0, 0);
      }
    if (c < 7) {
#pragma unroll
      for (int nt = 0; nt < 4; ++nt) {
        bh[nt] = *(const bf16x8*)&w2h[(c + 1) * 8192 + boff[nt]];
        bl[nt] = *(const bf16x8*)&w2l[(c + 1) * 8192 + boff[nt]];
      }
    }
  }

  // ---- epilogue: s row-sums only ----
  float wsr[4], b2v[4];
#pragma unroll
  for (int nt = 0; nt < 4; ++nt) {
    int col = wv * 64 + nt * 16 + c0;
    wsr[nt] = wsv[col]; b2v[nt] = b2[col];
  }
#pragma unroll
  for (int mt = 0; mt < 4; ++mt) {
    float srow[4] = {0.f, 0.f, 0.f, 0.f};
#pragma unroll
    for (int nt = 0; nt < 4; ++nt) {
      f32x4 z = acc[mt][nt];
#pragma unroll
      for (int r = 0; r < 4; ++r)
        srow[r] = fmaf(fmaxf(z[r] + b2v[nt], 0.f), wsr[nt], srow[r]);
    }
#pragma unroll
    for (int r = 0; r < 4; ++r) {
#pragma unroll
      for (int off = 1; off <= 8; off <<= 1) srow[r] += __shfl_xor(srow[r], off);
      if (c0 == 0) spart[(mt * 16 + g * 4 + r) * 4 + wv] = srow[r];
    }
  }
  __syncthreads();
  if (t < 64) {
    float s = bs[0] + spart[t * 4] + spart[t * 4 + 1] + spart[t * 4 + 2] + spart[t * 4 + 3];
    s_raw[m0 + t] = s;
    float s2 = s * s;
#pragma unroll
    for (int off = 32; off >= 1; off >>= 1) {
      s += __shfl_down(s, off);
      s2 += __shfl_down(s2, off);
    }
    if (t == 0) {
      atomicAdd(&stats_f[SI_SUMS], s);
      atomicAdd(&stats_f[SI_SUMS2], s2);
    }
  }
}

// ---------------- K2: fused scores + LDS hist + scan + scatter + rank (full TOPK) ----------------
__global__ __launch_bounds__(1024) void k_sel(
    const float* __restrict__ s_raw, float* stats_f,
    const float* __restrict__ gamma, const float* __restrict__ beta,
    unsigned* __restrict__ suf_g, ull* __restrict__ cand,
    int* __restrict__ flat_idx, float* __restrict__ sw_raw)
{
  __shared__ __align__(16) unsigned lh[NBUCK];      // 64 KB
  __shared__ unsigned wsum[16], wsuf[16];
  __shared__ unsigned sb_cut, sb_tot;
  __shared__ float esel_sh[16];
  const int batch = blockIdx.x, t = threadIdx.x;
  const int lane = t & 63, w = t >> 6;
  const float mu = stats_f[SI_SUMS] * (1.f / 65536.f);
  const float ex2 = stats_f[SI_SUMS2] * (1.f / 65536.f);
  const float istd = 1.f / sqrtf(ex2 - mu * mu + 1e-5f);
  const float gm = gamma[0], be = beta[0];
  if (t == 0) { sb_cut = 0u; sb_tot = PPB; }
#pragma unroll
  for (int j = 0; j < 16; ++j) lh[j * 1024 + t] = 0u;
  __syncthreads();
  float sc_loc[16];
#pragma unroll
  for (int j = 0; j < 16; ++j) {
    float sc = fmaxf((s_raw[batch * PPB + j * 1024 + t] - mu) * istd * gm + be, 0.f);
    sc_loc[j] = sc;
    unsigned bucket = __float_as_uint(sc) >> 17;
    if (bucket > NBUCK - 1u) bucket = NBUCK - 1u;
    if (bucket >= 1u) atomicAdd(&lh[bucket], 1u);
  }
  __syncthreads();
  unsigned hl[16]; unsigned ct = 0;
#pragma unroll
  for (int i = 0; i < 16; ++i) { hl[i] = lh[t * 16 + i]; ct += hl[i]; }
  unsigned x = ct;
#pragma unroll
  for (int off = 1; off <= 32; off <<= 1) {
    unsigned v = __shfl_down(x, off);
    if (lane + off < 64) x += v;
  }
  if (lane == 0) wsum[w] = x;
  __syncthreads();
  if (t < 16) {
    unsigned s = 0;
    for (int j = t + 1; j < 16; ++j) s += wsum[j];
    wsuf[t] = s;
  }
  __syncthreads();
  unsigned run = wsuf[w] + (x - ct);
  for (int i = 15; i >= 0; --i) {
    int b = t * 16 + i;
    unsigned h = hl[i];
    lh[b] = run;
    if (b >= 1 && run < TOPK && run + h >= TOPK) { sb_cut = (unsigned)b; sb_tot = run + h; }
    run += h;
  }
  if (t == 0 && run < TOPK) { sb_cut = 0u; sb_tot = PPB; }
  __syncthreads();
#pragma unroll
  for (int j = 0; j < 16; ++j) suf_g[batch * NBUCK + j * 1024 + t] = lh[j * 1024 + t];
  __syncthreads();
  const unsigned cut = sb_cut, tot = sb_tot;
#pragma unroll
  for (int j = 0; j < 16; ++j) {
    unsigned bits = __float_as_uint(sc_loc[j]);
    unsigned bucket = bits >> 17;
    if (bucket > NBUCK - 1u) bucket = NBUCK - 1u;
    if (bucket >= cut) {
      unsigned pos = atomicAdd(&lh[bucket], 1u);
      cand[batch * PPB + pos] =
          ((ull)bits << 32) | (ull)(~(unsigned)(batch * PPB + j * 1024 + t));
    }
  }
  __threadfence();
  __syncthreads();
  // cursors dead now — reuse lh's 64 KB as ull candidate cache for the rank scan
  ull* cl = (ull*)lh;
  const bool use_lds = (tot <= 8192u);
  if (use_lds)
    for (unsigned pos = t; pos < tot; pos += 1024) cl[pos] = cand[batch * PPB + pos];
  __syncthreads();
  const ull* seg = use_lds ? (const ull*)cl : &cand[batch * PPB];
  float esel = 0.f;
  for (int pos = t; pos < (int)tot; pos += 1024) {
    ull key = seg[pos];
    unsigned bits = (unsigned)(key >> 32);
    unsigned bucket = bits >> 17;
    unsigned s0 = suf_g[batch * NBUCK + bucket];
    unsigned s1 = (bucket >= 1u) ? suf_g[batch * NBUCK + bucket - 1] : tot;
    unsigned rank = s0;
    for (unsigned p = s0; p < s1; ++p) rank += (seg[p] > key);
    if (rank < TOPK) {
      float E = expf((__uint_as_float(bits) - 5.f) * 10.f);
      flat_idx[batch * TOPK + rank] = (int)(~(unsigned)key);
      sw_raw[batch * TOPK + rank] = E;
      esel += E;
    }
  }
#pragma unroll
  for (int off = 32; off >= 1; off >>= 1) esel += __shfl_down(esel, off);
  if (lane == 0) esel_sh[w] = esel;
  __syncthreads();
  if (t == 0) {
    float s = 0.f;
    for (int j = 0; j < 16; ++j) s += esel_sh[j];
    stats_f[SI_ESEL + batch] = s;
  }
}

// ---------------- K3: fused double-GEMM processor, M=64/block (all ranks) ----------------
__global__ __launch_bounds__(256, 2) void k_proc(
    const float4* __restrict__ pts4, const float* __restrict__ w1,
    const float* __restrict__ b1,
    const unsigned short* __restrict__ w2h, const unsigned short* __restrict__ w2l,
    const float* __restrict__ b2,
    const float* stats_f, const int* __restrict__ flat_idx,
    const float* __restrict__ sw_raw,
    const unsigned short* __restrict__ p1h, const unsigned short* __restrict__ p1l,
    const float* __restrict__ bp1,
    const float4* __restrict__ wp2_4, const float* __restrict__ bp2,
    float4* __restrict__ out4)
{
  __shared__ float w1_l[1024];
  __shared__ float b1_l[256];
  __shared__ int idx_t[64];
  __shared__ float sw_t[64];
  __shared__ __align__(16) short sf_s[16384];   // 32 KB: 8 slabs [64 x 32k] swizzled
  __shared__ float opart[4 * 64 * 4];

  const int t = threadIdx.x;
  const int m0 = blockIdx.x * 64;
  const int b = m0 >> 12;
  const int wv = t >> 6, lane = t & 63, g = lane >> 4, c0 = lane & 15;

#pragma unroll
  for (int i = 0; i < 4; ++i) w1_l[i * 256 + t] = w1[i * 256 + t];
  b1_l[t] = b1[t];
  if (t < 64) {
    idx_t[t] = flat_idx[m0 + t];
    sw_t[t] = sw_raw[m0 + t] / stats_f[SI_ESEL + b];
  }
  f32x4 acc[4][4];
#pragma unroll
  for (int i = 0; i < 4; ++i)
#pragma unroll
    for (int j = 0; j < 4; ++j) acc[i][j] = (f32x4){0.f, 0.f, 0.f, 0.f};
  __syncthreads();

  float4 pr[4];
#pragma unroll
  for (int mt = 0; mt < 4; ++mt) pr[mt] = pts4[idx_t[mt * 16 + c0]];
  float swr[4][4];
#pragma unroll
  for (int mt = 0; mt < 4; ++mt)
#pragma unroll
    for (int r = 0; r < 4; ++r) swr[mt][r] = sw_t[mt * 16 + g * 4 + r];

  int boff[4];
#pragma unroll
  for (int nt = 0; nt < 4; ++nt) {
    int n = wv * 64 + nt * 16 + c0;
    boff[nt] = n * 32 + ((g ^ ((n >> 1) & 3)) << 3);
  }

  // ===== GEMM1: z1 = h @ w2 (A = RTNE bf16 of h; B = w2 hi/lo 2-chain) =====
  bf16x8 bh[4], bl[4];
#pragma unroll
  for (int nt = 0; nt < 4; ++nt) {
    bh[nt] = *(const bf16x8*)&w2h[boff[nt]];
    bl[nt] = *(const bf16x8*)&w2l[boff[nt]];
  }
  for (int c = 0; c < 8; ++c) {
    const int kb = c * 32 + g * 8;
    float wk0[8], wk1[8], wk2[8], wk3[8], bk[8];
    *(float4*)&wk0[0] = *(const float4*)&w1_l[kb];
    *(float4*)&wk0[4] = *(const float4*)&w1_l[kb + 4];
    *(float4*)&wk1[0] = *(const float4*)&w1_l[256 + kb];
    *(float4*)&wk1[4] = *(const float4*)&w1_l[256 + kb + 4];
    *(float4*)&wk2[0] = *(const float4*)&w1_l[512 + kb];
    *(float4*)&wk2[4] = *(const float4*)&w1_l[512 + kb + 4];
    *(float4*)&wk3[0] = *(const float4*)&w1_l[768 + kb];
    *(float4*)&wk3[4] = *(const float4*)&w1_l[768 + kb + 4];
    *(float4*)&bk[0] = *(const float4*)&b1_l[kb];
    *(float4*)&bk[4] = *(const float4*)&b1_l[kb + 4];

    bf16x8 ah[4];
#pragma unroll
    for (int mt = 0; mt < 4; ++mt) {
      float4 pv = pr[mt];
      frag_u uh;
#pragma unroll
      for (int jp = 0; jp < 4; ++jp) {
        int j0 = 2 * jp, j1 = 2 * jp + 1;
        float h0 = fmaf(pv.w, wk3[j0], fmaf(pv.z, wk2[j0],
                   fmaf(pv.y, wk1[j0], fmaf(pv.x, wk0[j0], bk[j0]))));
        float h1 = fmaf(pv.w, wk3[j1], fmaf(pv.z, wk2[j1],
                   fmaf(pv.y, wk1[j1], fmaf(pv.x, wk0[j1], bk[j1]))));
        uh.d[jp] = (unsigned)f2bf(fmaxf(h0, 0.f)) |
                   ((unsigned)f2bf(fmaxf(h1, 0.f)) << 16);
      }
      ah[mt] = uh.v;
    }
#pragma unroll
    for (int mt = 0; mt < 4; ++mt)
#pragma unroll
      for (int nt = 0; nt < 4; ++nt) {
        acc[mt][nt] = __builtin_amdgcn_mfma_f32_16x16x32_bf16(ah[mt], bh[nt], acc[mt][nt], 0, 0, 0);
        acc[mt][nt] = __builtin_amdgcn_mfma_f32_16x16x32_bf16(ah[mt], bl[nt], acc[mt][nt], 0, 0, 0);
      }
    if (c < 7) {
#pragma unroll
      for (int nt = 0; nt < 4; ++nt) {
        bh[nt] = *(const bf16x8*)&w2h[(c + 1) * 8192 + boff[nt]];
        bl[nt] = *(const bf16x8*)&w2l[(c + 1) * 8192 + boff[nt]];
      }
    }
  }

  // ===== transform: sf = relu(z1 + b2) * sw  ->  LDS bf16, A-layout swizzle =====
  {
    float b2v[4];
#pragma unroll
    for (int nt = 0; nt < 4; ++nt) b2v[nt] = b2[wv * 64 + nt * 16 + c0];
#pragma unroll
    for (int mt = 0; mt < 4; ++mt)
#pragma unroll
      for (int nt = 0; nt < 4; ++nt) {
        int n = wv * 64 + nt * 16 + c0;
        int slab = n >> 5, qc = (n >> 3) & 3, kof = n & 7;
#pragma unroll
        for (int r = 0; r < 4; ++r) {
          int m = mt * 16 + g * 4 + r;
          float v = fmaxf(acc[mt][nt][r] + b2v[nt], 0.f) * swr[mt][r];
          sf_s[slab * 2048 + m * 32 + ((qc ^ ((m >> 1) & 3)) << 3) + kof] = f2bf(v);
        }
      }
  }
  __syncthreads();

  // ===== GEMM2: y = sf @ wp1 (A = sf bf16; B = wp1 hi/lo 2-chain) =====
#pragma unroll
  for (int i = 0; i < 4; ++i)
#pragma unroll
    for (int j = 0; j < 4; ++j) acc[i][j] = (f32x4){0.f, 0.f, 0.f, 0.f};
#pragma unroll
  for (int nt = 0; nt < 4; ++nt) {
    bh[nt] = *(const bf16x8*)&p1h[boff[nt]];
    bl[nt] = *(const bf16x8*)&p1l[boff[nt]];
  }
  for (int c = 0; c < 8; ++c) {
#pragma unroll
    for (int mt = 0; mt < 4; ++mt) {
      int m = mt * 16 + c0;
      bf16x8 af = *(const bf16x8*)&sf_s[c * 2048 + m * 32 + ((g ^ ((m >> 1) & 3)) << 3)];
#pragma unroll
      for (int nt = 0; nt < 4; ++nt) {
        acc[mt][nt] = __builtin_amdgcn_mfma_f32_16x16x32_bf16(af, bh[nt], acc[mt][nt], 0, 0, 0);
        acc[mt][nt] = __builtin_amdgcn_mfma_f32_16x16x32_bf16(af, bl[nt], acc[mt][nt], 0, 0, 0);
      }
    }
    if (c < 7) {
#pragma unroll
      for (int nt = 0; nt < 4; ++nt) {
        bh[nt] = *(const bf16x8*)&p1h[(c + 1) * 8192 + boff[nt]];
        bl[nt] = *(const bf16x8*)&p1l[(c + 1) * 8192 + boff[nt]];
      }
    }
  }

  // ===== epilogue: out = relu(y + bp1) @ wp2 + bp2 (sw already applied) =====
  float4 wq[4]; float bp1v[4];
#pragma unroll
  for (int nt = 0; nt < 4; ++nt) {
    int n = wv * 64 + nt * 16 + c0;
    wq[nt] = wp2_4[n]; bp1v[nt] = bp1[n];
  }
#pragma unroll
  for (int mt = 0; mt < 4; ++mt) {
#pragma unroll
    for (int r = 0; r < 4; ++r) {
      float4 o = {0.f, 0.f, 0.f, 0.f};
#pragma unroll
      for (int nt = 0; nt < 4; ++nt) {
        float y = fmaxf(acc[mt][nt][r] + bp1v[nt], 0.f);
        o.x = fmaf(y, wq[nt].x, o.x); o.y = fmaf(y, wq[nt].y, o.y);
        o.z = fmaf(y, wq[nt].z, o.z); o.w = fmaf(y, wq[nt].w, o.w);
      }
#pragma unroll
      for (int off = 1; off <= 8; off <<= 1) {
        o.x += __shfl_xor(o.x, off); o.y += __shfl_xor(o.y, off);
        o.z += __shfl_xor(o.z, off); o.w += __shfl_xor(o.w, off);
      }
      if (c0 == 0) *(float4*)&opart[(wv * 64 + mt * 16 + g * 4 + r) * 4] = o;
    }
  }
  __syncthreads();
  if (t < 64) {
    float4 bp2v = *(const float4*)bp2;
    float4 s0 = *(float4*)&opart[t * 4];
    float4 s1 = *(float4*)&opart[(64 + t) * 4];
    float4 s2 = *(float4*)&opart[(128 + t) * 4];
    float4 s3 = *(float4*)&opart[(192 + t) * 4];
    float4 r;
    r.x = s0.x + s1.x + s2.x + s3.x + bp2v.x;
    r.y = s0.y + s1.y + s2.y + s3.y + bp2v.y;
    r.z = s0.z + s1.z + s2.z + s3.z + bp2v.z;
    r.w = s0.w + s1.w + s2.w + s3.w + bp2v.w;
    out4[m0 + t] = r;
  }
}

extern "C" void kernel_launch(void* const* d_in, const int* in_sizes, int n_in,
                              void* d_out, int out_size, void* d_ws, size_t ws_size,
                              hipStream_t stream) {
  const float* pts   = (const float*)d_in[0];
  const float* w1    = (const float*)d_in[1];
  const float* b1    = (const float*)d_in[2];
  const float* w2    = (const float*)d_in[3];
  const float* b2    = (const float*)d_in[4];
  const float* wsv   = (const float*)d_in[5];
  const float* bs    = (const float*)d_in[6];
  const float* gamma = (const float*)d_in[7];
  const float* beta  = (const float*)d_in[8];
  const float* wp1   = (const float*)d_in[9];
  const float* bp1   = (const float*)d_in[10];
  const float* wp2   = (const float*)d_in[11];
  const float* bp2   = (const float*)d_in[12];

  char* wsb = (char*)d_ws;
  float*    s_raw   = (float*)(wsb + SRAW_OFF);
  float*    stats_f = (float*)(wsb + ST_OFF);
  unsigned* suf     = (unsigned*)(wsb + SUF_OFF);
  ull*      cand    = (ull*)(wsb + CAND_OFF);
  int*      flat_i  = (int*)(wsb + FIDX_OFF);
  float*    sw_raw  = (float*)(wsb + SW_OFF);
  unsigned short* w2h = (unsigned short*)(wsb + W2SH_OFF);
  unsigned short* w2l = (unsigned short*)(wsb + W2SL_OFF);
  unsigned short* p1h = (unsigned short*)(wsb + WP1H_OFF);
  unsigned short* p1l = (unsigned short*)(wsb + WP1L_OFF);

  hipLaunchKernelGGL(k_prep, dim3(17), dim3(256), 0, stream,
                     w2, wp1, w2h, w2l, p1h, p1l, stats_f);
  hipLaunchKernelGGL(k_mlp, dim3(1024), dim3(256), 0, stream,
                     (const float4*)pts, w1, b1, w2h, w2l, b2, wsv, bs,
                     s_raw, stats_f);
  hipLaunchKernelGGL(k_sel, dim3(NB), dim3(1024), 0, stream,
                     s_raw, stats_f, gamma, beta, suf, cand, flat_i, sw_raw);
  hipLaunchKernelGGL(k_proc, dim3(256), dim3(256), 0, stream,
                     (const float4*)pts, w1, b1, w2h, w2l, b2,
                     stats_f, flat_i, sw_raw, p1h, p1l, bp1,
                     (const float4*)wp2, bp2, (float4*)d_out);
}

// Round 13
// 173.133 us; speedup vs baseline: 1.1956x; 1.0908x over previous
//
#include <hip/hip_runtime.h>
#include <math.h>

typedef unsigned long long ull;
typedef __attribute__((ext_vector_type(8))) short bf16x8;
typedef __attribute__((ext_vector_type(4))) float f32x4;

#define PPB   16384
#define NB    4
#define TOPK  4096
#define NPTS  65536
#define NBUCK 16384
#define BSCALE 2048.0f   // linear monotone bucketing: ~1-3 pts/bucket (scores plateau near max)

// workspace layout (bytes)
#define SRAW_OFF  0u          // N f32 (256 KB)
#define ST_OFF    262144u     // 64 words stats
#define SUF_OFF   262400u     // 4*16384 u32 (256 KB)
#define CAND_OFF  524544u     // 4*16384 u64 (512 KB)
#define FIDX_OFF  1048832u    // 16384 i32
#define SW_OFF    1114368u    // 16384 f32
#define W2SH_OFF  1179904u    // 256*256 bf16 chunk-swizzled image (hi)
#define W2SL_OFF  1310976u    // (lo)
#define WP1H_OFF  1442048u    // wp1^T image (hi)
#define WP1L_OFF  1573120u    // (lo)   end 1704192

// stats word indices
#define SI_SUMS  0
#define SI_SUMS2 1
#define SI_ESEL  12  // ..15 per-batch sum exp (selected)

union frag_u { unsigned d[4]; bf16x8 v; uint4 q; };

__device__ __forceinline__ unsigned short f2bf(float f) {
  unsigned u = __float_as_uint(f);
  unsigned r = 0x7FFFu + ((u >> 16) & 1u);   // RTNE
  return (unsigned short)((u + r) >> 16);
}
__device__ __forceinline__ float bf2f(unsigned short h) {
  return __uint_as_float((unsigned)h << 16);
}
__device__ __forceinline__ unsigned sc2bucket(float sc) {
  unsigned b = (unsigned)(sc * BSCALE);      // monotone in sc (sc >= 0)
  return b > NBUCK - 1u ? NBUCK - 1u : b;
}

// ---------------- prep: images (coalesced) + stats zeroing ----------------
__global__ __launch_bounds__(256) void k_prep(
    const float* __restrict__ w2, const float* __restrict__ wp1,
    unsigned short* __restrict__ w2h, unsigned short* __restrict__ w2l,
    unsigned short* __restrict__ p1h, unsigned short* __restrict__ p1l,
    float* __restrict__ stats)
{
  const int t = threadIdx.x, bx = blockIdx.x;
  if (bx >= 16) {
    if (t < 64) stats[t] = 0.f;
    return;
  }
  __shared__ unsigned short lh[8192], ll[8192];
  const int c = bx & 7;
  const float* src = (bx >= 8) ? wp1 : w2;
  unsigned short* dh = (bx >= 8) ? p1h : w2h;
  unsigned short* dl = (bx >= 8) ? p1l : w2l;
  const int sw = (t >> 1) & 3;
#pragma unroll
  for (int kk = 0; kk < 32; ++kk) {
    float v = src[(c * 32 + kk) * 256 + t];      // coalesced 256-wide
    unsigned short h = f2bf(v);
    int q = kk >> 3, kof = kk & 7;
    int off = t * 32 + ((q ^ sw) << 3) + kof;
    lh[off] = h;
    ll[off] = f2bf(v - bf2f(h));
  }
  __syncthreads();
#pragma unroll
  for (int u = 0; u < 4; ++u) {
    ((uint4*)&dh[c * 8192])[u * 256 + t] = ((const uint4*)lh)[u * 256 + t];
    ((uint4*)&dl[c * 8192])[u * 256 + t] = ((const uint4*)ll)[u * 256 + t];
  }
}

// ---------------- K1: score-only point MLP, M=64/block (best known: ~48us) ----------------
// (256,2) ONLY: VGPR demand ~150; tighter bounds spill to scratch (R4/R6/R8).
__global__ __launch_bounds__(256, 2) void k_mlp(
    const float4* __restrict__ pts4, const float* __restrict__ w1,
    const float* __restrict__ b1,
    const unsigned short* __restrict__ w2h, const unsigned short* __restrict__ w2l,
    const float* __restrict__ b2, const float* __restrict__ wsv,
    const float* __restrict__ bs,
    float* __restrict__ s_raw, float* stats_f)
{
  __shared__ float w1_l[1024];
  __shared__ float b1_l[256];
  __shared__ float pts_l[256];
  __shared__ float spart[256];

  const int t = threadIdx.x;
  const int m0 = blockIdx.x * 64;
  const int wv = t >> 6, lane = t & 63, g = lane >> 4, c0 = lane & 15;

#pragma unroll
  for (int i = 0; i < 4; ++i) w1_l[i * 256 + t] = w1[i * 256 + t];
  b1_l[t] = b1[t];
  if (t < 64) ((float4*)pts_l)[t] = pts4[m0 + t];

  f32x4 acc[4][4];
#pragma unroll
  for (int i = 0; i < 4; ++i)
#pragma unroll
    for (int j = 0; j < 4; ++j) acc[i][j] = (f32x4){0.f, 0.f, 0.f, 0.f};
  __syncthreads();

  float4 pr[4];
#pragma unroll
  for (int mt = 0; mt < 4; ++mt) pr[mt] = ((const float4*)pts_l)[mt * 16 + c0];

  int boff[4];
#pragma unroll
  for (int nt = 0; nt < 4; ++nt) {
    int n = wv * 64 + nt * 16 + c0;
    boff[nt] = n * 32 + ((g ^ ((n >> 1) & 3)) << 3);
  }
  bf16x8 bh[4], bl[4];
#pragma unroll
  for (int nt = 0; nt < 4; ++nt) {
    bh[nt] = *(const bf16x8*)&w2h[boff[nt]];
    bl[nt] = *(const bf16x8*)&w2l[boff[nt]];
  }

  for (int c = 0; c < 8; ++c) {
    const int kb = c * 32 + g * 8;
    float wk0[8], wk1[8], wk2[8], wk3[8], bk[8];
    *(float4*)&wk0[0] = *(const float4*)&w1_l[kb];
    *(float4*)&wk0[4] = *(const float4*)&w1_l[kb + 4];
    *(float4*)&wk1[0] = *(const float4*)&w1_l[256 + kb];
    *(float4*)&wk1[4] = *(const float4*)&w1_l[256 + kb + 4];
    *(float4*)&wk2[0] = *(const float4*)&w1_l[512 + kb];
    *(float4*)&wk2[4] = *(const float4*)&w1_l[512 + kb + 4];
    *(float4*)&wk3[0] = *(const float4*)&w1_l[768 + kb];
    *(float4*)&wk3[4] = *(const float4*)&w1_l[768 + kb + 4];
    *(float4*)&bk[0] = *(const float4*)&b1_l[kb];
    *(float4*)&bk[4] = *(const float4*)&b1_l[kb + 4];

    bf16x8 ah[4], al[4];
#pragma unroll
    for (int mt = 0; mt < 4; ++mt) {
      float4 pv = pr[mt];
      frag_u uh, ul;
#pragma unroll
      for (int jp = 0; jp < 4; ++jp) {
        int j0 = 2 * jp, j1 = 2 * jp + 1;
        float h0 = fmaf(pv.w, wk3[j0], fmaf(pv.z, wk2[j0],
                   fmaf(pv.y, wk1[j0], fmaf(pv.x, wk0[j0], bk[j0]))));
        float h1 = fmaf(pv.w, wk3[j1], fmaf(pv.z, wk2[j1],
                   fmaf(pv.y, wk1[j1], fmaf(pv.x, wk0[j1], bk[j1]))));
        h0 = fmaxf(h0, 0.f); h1 = fmaxf(h1, 0.f);
        unsigned u0 = __float_as_uint(h0), u1 = __float_as_uint(h1);
        uh.d[jp] = (u0 >> 16) | (u1 & 0xFFFF0000u);
        float r0 = h0 - __uint_as_float(u0 & 0xFFFF0000u);
        float r1 = h1 - __uint_as_float(u1 & 0xFFFF0000u);
        ul.d[jp] = (__float_as_uint(r0) >> 16) | (__float_as_uint(r1) & 0xFFFF0000u);
      }
      ah[mt] = uh.v; al[mt] = ul.v;
    }
#pragma unroll
    for (int mt = 0; mt < 4; ++mt)
#pragma unroll
      for (int nt = 0; nt < 4; ++nt) {
        acc[mt][nt] = __builtin_amdgcn_mfma_f32_16x16x32_bf16(ah[mt], bh[nt], acc[mt][nt], 0, 0, 0);
        acc[mt][nt] = __builtin_amdgcn_mfma_f32_16x16x32_bf16(al[mt], bh[nt], acc[mt][nt], 0, 0, 0);
        acc[mt][nt] = __builtin_amdgcn_mfma_f32_16x16x32_bf16(ah[mt], bl[nt], acc[mt][nt], 0, 0, 0);
      }
    if (c < 7) {
#pragma unroll
      for (int nt = 0; nt < 4; ++nt) {
        bh[nt] = *(const bf16x8*)&w2h[(c + 1) * 8192 + boff[nt]];
        bl[nt] = *(const bf16x8*)&w2l[(c + 1) * 8192 + boff[nt]];
      }
    }
  }

  // ---- epilogue: s row-sums only ----
  float wsr[4], b2v[4];
#pragma unroll
  for (int nt = 0; nt < 4; ++nt) {
    int col = wv * 64 + nt * 16 + c0;
    wsr[nt] = wsv[col]; b2v[nt] = b2[col];
  }
#pragma unroll
  for (int mt = 0; mt < 4; ++mt) {
    float srow[4] = {0.f, 0.f, 0.f, 0.f};
#pragma unroll
    for (int nt = 0; nt < 4; ++nt) {
      f32x4 z = acc[mt][nt];
#pragma unroll
      for (int r = 0; r < 4; ++r)
        srow[r] = fmaf(fmaxf(z[r] + b2v[nt], 0.f), wsr[nt], srow[r]);
    }
#pragma unroll
    for (int r = 0; r < 4; ++r) {
#pragma unroll
      for (int off = 1; off <= 8; off <<= 1) srow[r] += __shfl_xor(srow[r], off);
      if (c0 == 0) spart[(mt * 16 + g * 4 + r) * 4 + wv] = srow[r];
    }
  }
  __syncthreads();
  if (t < 64) {
    float s = bs[0] + spart[t * 4] + spart[t * 4 + 1] + spart[t * 4 + 2] + spart[t * 4 + 3];
    s_raw[m0 + t] = s;
    float s2 = s * s;
#pragma unroll
    for (int off = 32; off >= 1; off >>= 1) {
      s += __shfl_down(s, off);
      s2 += __shfl_down(s2, off);
    }
    if (t == 0) {
      atomicAdd(&stats_f[SI_SUMS], s);
      atomicAdd(&stats_f[SI_SUMS2], s2);
    }
  }
}

// ---------------- K2: fused scores + LDS hist + scan + scatter + rank ----------------
// Linear monotone bucketing (sc*BSCALE) spreads the plateau-clustered scores
// over thousands of buckets: ~10x less LDS-atomic contention, short segments.
__global__ __launch_bounds__(1024) void k_sel(
    const float* __restrict__ s_raw, float* stats_f,
    const float* __restrict__ gamma, const float* __restrict__ beta,
    unsigned* __restrict__ suf_g, ull* __restrict__ cand,
    int* __restrict__ flat_idx, float* __restrict__ sw_raw)
{
  __shared__ __align__(16) unsigned lh[NBUCK];      // 64 KB
  __shared__ unsigned wsum[16], wsuf[16];
  __shared__ unsigned sb_cut, sb_tot;
  __shared__ float esel_sh[16];
  const int batch = blockIdx.x, t = threadIdx.x;
  const int lane = t & 63, w = t >> 6;
  const float mu = stats_f[SI_SUMS] * (1.f / 65536.f);
  const float ex2 = stats_f[SI_SUMS2] * (1.f / 65536.f);
  const float istd = 1.f / sqrtf(ex2 - mu * mu + 1e-5f);
  const float gm = gamma[0], be = beta[0];
  if (t == 0) { sb_cut = 0u; sb_tot = PPB; }
#pragma unroll
  for (int j = 0; j < 16; ++j) lh[j * 1024 + t] = 0u;
  __syncthreads();
  float sc_loc[16];
#pragma unroll
  for (int j = 0; j < 16; ++j) {
    float sc = fmaxf((s_raw[batch * PPB + j * 1024 + t] - mu) * istd * gm + be, 0.f);
    sc_loc[j] = sc;
    unsigned bucket = sc2bucket(sc);
    if (bucket >= 1u) atomicAdd(&lh[bucket], 1u);
  }
  __syncthreads();
  unsigned hl[16]; unsigned ct = 0;
#pragma unroll
  for (int i = 0; i < 16; ++i) { hl[i] = lh[t * 16 + i]; ct += hl[i]; }
  unsigned x = ct;
#pragma unroll
  for (int off = 1; off <= 32; off <<= 1) {
    unsigned v = __shfl_down(x, off);
    if (lane + off < 64) x += v;
  }
  if (lane == 0) wsum[w] = x;
  __syncthreads();
  if (t < 16) {
    unsigned s = 0;
    for (int j = t + 1; j < 16; ++j) s += wsum[j];
    wsuf[t] = s;
  }
  __syncthreads();
  unsigned run = wsuf[w] + (x - ct);
  for (int i = 15; i >= 0; --i) {
    int b = t * 16 + i;
    unsigned h = hl[i];
    lh[b] = run;
    if (b >= 1 && run < TOPK && run + h >= TOPK) { sb_cut = (unsigned)b; sb_tot = run + h; }
    run += h;
  }
  if (t == 0 && run < TOPK) { sb_cut = 0u; sb_tot = PPB; }
  __syncthreads();
#pragma unroll
  for (int j = 0; j < 16; ++j) suf_g[batch * NBUCK + j * 1024 + t] = lh[j * 1024 + t];
  __syncthreads();
  const unsigned cut = sb_cut, tot = sb_tot;
#pragma unroll
  for (int j = 0; j < 16; ++j) {
    float sc = sc_loc[j];
    unsigned bucket = sc2bucket(sc);
    if (bucket >= cut) {
      unsigned pos = atomicAdd(&lh[bucket], 1u);
      cand[batch * PPB + pos] =
          ((ull)__float_as_uint(sc) << 32) | (ull)(~(unsigned)(batch * PPB + j * 1024 + t));
    }
  }
  __threadfence();
  __syncthreads();
  // cursors dead now — reuse lh's 64 KB as ull candidate cache for the rank scan
  ull* cl = (ull*)lh;
  const bool use_lds = (tot <= 8192u);
  if (use_lds)
    for (unsigned pos = t; pos < tot; pos += 1024) cl[pos] = cand[batch * PPB + pos];
  __syncthreads();
  const ull* seg = use_lds ? (const ull*)cl : &cand[batch * PPB];
  float esel = 0.f;
  for (int pos = t; pos < (int)tot; pos += 1024) {
    ull key = seg[pos];
    unsigned bits = (unsigned)(key >> 32);
    unsigned bucket = sc2bucket(__uint_as_float(bits));
    unsigned s0 = suf_g[batch * NBUCK + bucket];
    unsigned s1 = (bucket >= 1u) ? suf_g[batch * NBUCK + bucket - 1] : tot;
    unsigned rank = s0;
    for (unsigned p = s0; p < s1; ++p) rank += (seg[p] > key);
    if (rank < TOPK) {
      float E = expf((__uint_as_float(bits) - 5.f) * 10.f);
      flat_idx[batch * TOPK + rank] = (int)(~(unsigned)key);
      sw_raw[batch * TOPK + rank] = E;
      esel += E;
    }
  }
#pragma unroll
  for (int off = 32; off >= 1; off >>= 1) esel += __shfl_down(esel, off);
  if (lane == 0) esel_sh[w] = esel;
  __syncthreads();
  if (t == 0) {
    float s = 0.f;
    for (int j = 0; j < 16; ++j) s += esel_sh[j];
    stats_f[SI_ESEL + batch] = s;
  }
}

// ---------------- K3: fused double-GEMM processor, M=64/block (all ranks) ----------------
__global__ __launch_bounds__(256, 2) void k_proc(
    const float4* __restrict__ pts4, const float* __restrict__ w1,
    const float* __restrict__ b1,
    const unsigned short* __restrict__ w2h, const unsigned short* __restrict__ w2l,
    const float* __restrict__ b2,
    const float* stats_f, const int* __restrict__ flat_idx,
    const float* __restrict__ sw_raw,
    const unsigned short* __restrict__ p1h, const unsigned short* __restrict__ p1l,
    const float* __restrict__ bp1,
    const float4* __restrict__ wp2_4, const float* __restrict__ bp2,
    float4* __restrict__ out4)
{
  __shared__ float w1_l[1024];
  __shared__ float b1_l[256];
  __shared__ int idx_t[64];
  __shared__ float sw_t[64];
  __shared__ __align__(16) short sf_s[16384];   // 32 KB: 8 slabs [64 x 32k] swizzled
  __shared__ float opart[4 * 64 * 4];

  const int t = threadIdx.x;
  const int m0 = blockIdx.x * 64;
  const int b = m0 >> 12;
  const int wv = t >> 6, lane = t & 63, g = lane >> 4, c0 = lane & 15;

#pragma unroll
  for (int i = 0; i < 4; ++i) w1_l[i * 256 + t] = w1[i * 256 + t];
  b1_l[t] = b1[t];
  if (t < 64) {
    idx_t[t] = flat_idx[m0 + t];
    sw_t[t] = sw_raw[m0 + t] / stats_f[SI_ESEL + b];
  }
  f32x4 acc[4][4];
#pragma unroll
  for (int i = 0; i < 4; ++i)
#pragma unroll
    for (int j = 0; j < 4; ++j) acc[i][j] = (f32x4){0.f, 0.f, 0.f, 0.f};
  __syncthreads();

  float4 pr[4];
#pragma unroll
  for (int mt = 0; mt < 4; ++mt) pr[mt] = pts4[idx_t[mt * 16 + c0]];
  float swr[4][4];
#pragma unroll
  for (int mt = 0; mt < 4; ++mt)
#pragma unroll
    for (int r = 0; r < 4; ++r) swr[mt][r] = sw_t[mt * 16 + g * 4 + r];

  int boff[4];
#pragma unroll
  for (int nt = 0; nt < 4; ++nt) {
    int n = wv * 64 + nt * 16 + c0;
    boff[nt] = n * 32 + ((g ^ ((n >> 1) & 3)) << 3);
  }

  // ===== GEMM1: z1 = h @ w2 (A = RTNE bf16 of h; B = w2 hi/lo 2-chain) =====
  bf16x8 bh[4], bl[4];
#pragma unroll
  for (int nt = 0; nt < 4; ++nt) {
    bh[nt] = *(const bf16x8*)&w2h[boff[nt]];
    bl[nt] = *(const bf16x8*)&w2l[boff[nt]];
  }
  for (int c = 0; c < 8; ++c) {
    const int kb = c * 32 + g * 8;
    float wk0[8], wk1[8], wk2[8], wk3[8], bk[8];
    *(float4*)&wk0[0] = *(const float4*)&w1_l[kb];
    *(float4*)&wk0[4] = *(const float4*)&w1_l[kb + 4];
    *(float4*)&wk1[0] = *(const float4*)&w1_l[256 + kb];
    *(float4*)&wk1[4] = *(const float4*)&w1_l[256 + kb + 4];
    *(float4*)&wk2[0] = *(const float4*)&w1_l[512 + kb];
    *(float4*)&wk2[4] = *(const float4*)&w1_l[512 + kb + 4];
    *(float4*)&wk3[0] = *(const float4*)&w1_l[768 + kb];
    *(float4*)&wk3[4] = *(const float4*)&w1_l[768 + kb + 4];
    *(float4*)&bk[0] = *(const float4*)&b1_l[kb];
    *(float4*)&bk[4] = *(const float4*)&b1_l[kb + 4];

    bf16x8 ah[4];
#pragma unroll
    for (int mt = 0; mt < 4; ++mt) {
      float4 pv = pr[mt];
      frag_u uh;
#pragma unroll
      for (int jp = 0; jp < 4; ++jp) {
        int j0 = 2 * jp, j1 = 2 * jp + 1;
        float h0 = fmaf(pv.w, wk3[j0], fmaf(pv.z, wk2[j0],
                   fmaf(pv.y, wk1[j0], fmaf(pv.x, wk0[j0], bk[j0]))));
        float h1 = fmaf(pv.w, wk3[j1], fmaf(pv.z, wk2[j1],
                   fmaf(pv.y, wk1[j1], fmaf(pv.x, wk0[j1], bk[j1]))));
        uh.d[jp] = (unsigned)f2bf(fmaxf(h0, 0.f)) |
                   ((unsigned)f2bf(fmaxf(h1, 0.f)) << 16);
      }
      ah[mt] = uh.v;
    }
#pragma unroll
    for (int mt = 0; mt < 4; ++mt)
#pragma unroll
      for (int nt = 0; nt < 4; ++nt) {
        acc[mt][nt] = __builtin_amdgcn_mfma_f32_16x16x32_bf16(ah[mt], bh[nt], acc[mt][nt], 0, 0, 0);
        acc[mt][nt] = __builtin_amdgcn_mfma_f32_16x16x32_bf16(ah[mt], bl[nt], acc[mt][nt], 0, 0, 0);
      }
    if (c < 7) {
#pragma unroll
      for (int nt = 0; nt < 4; ++nt) {
        bh[nt] = *(const bf16x8*)&w2h[(c + 1) * 8192 + boff[nt]];
        bl[nt] = *(const bf16x8*)&w2l[(c + 1) * 8192 + boff[nt]];
      }
    }
  }

  // ===== transform: sf = relu(z1 + b2) * sw  ->  LDS bf16, A-layout swizzle =====
  {
    float b2v[4];
#pragma unroll
    for (int nt = 0; nt < 4; ++nt) b2v[nt] = b2[wv * 64 + nt * 16 + c0];
#pragma unroll
    for (int mt = 0; mt < 4; ++mt)
#pragma unroll
      for (int nt = 0; nt < 4; ++nt) {
        int n = wv * 64 + nt * 16 + c0;
        int slab = n >> 5, qc = (n >> 3) & 3, kof = n & 7;
#pragma unroll
        for (int r = 0; r < 4; ++r) {
          int m = mt * 16 + g * 4 + r;
          float v = fmaxf(acc[mt][nt][r] + b2v[nt], 0.f) * swr[mt][r];
          sf_s[slab * 2048 + m * 32 + ((qc ^ ((m >> 1) & 3)) << 3) + kof] = f2bf(v);
        }
      }
  }
  __syncthreads();

  // ===== GEMM2: y = sf @ wp1 (A = sf bf16; B = wp1 hi/lo 2-chain) =====
#pragma unroll
  for (int i = 0; i < 4; ++i)
#pragma unroll
    for (int j = 0; j < 4; ++j) acc[i][j] = (f32x4){0.f, 0.f, 0.f, 0.f};
#pragma unroll
  for (int nt = 0; nt < 4; ++nt) {
    bh[nt] = *(const bf16x8*)&p1h[boff[nt]];
    bl[nt] = *(const bf16x8*)&p1l[boff[nt]];
  }
  for (int c = 0; c < 8; ++c) {
#pragma unroll
    for (int mt = 0; mt < 4; ++mt) {
      int m = mt * 16 + c0;
      bf16x8 af = *(const bf16x8*)&sf_s[c * 2048 + m * 32 + ((g ^ ((m >> 1) & 3)) << 3)];
#pragma unroll
      for (int nt = 0; nt < 4; ++nt) {
        acc[mt][nt] = __builtin_amdgcn_mfma_f32_16x16x32_bf16(af, bh[nt], acc[mt][nt], 0, 0, 0);
        acc[mt][nt] = __builtin_amdgcn_mfma_f32_16x16x32_bf16(af, bl[nt], acc[mt][nt], 0, 0, 0);
      }
    }
    if (c < 7) {
#pragma unroll
      for (int nt = 0; nt < 4; ++nt) {
        bh[nt] = *(const bf16x8*)&p1h[(c + 1) * 8192 + boff[nt]];
        bl[nt] = *(const bf16x8*)&p1l[(c + 1) * 8192 + boff[nt]];
      }
    }
  }

  // ===== epilogue: out = relu(y + bp1) @ wp2 + bp2 (sw already applied) =====
  float4 wq[4]; float bp1v[4];
#pragma unroll
  for (int nt = 0; nt < 4; ++nt) {
    int n = wv * 64 + nt * 16 + c0;
    wq[nt] = wp2_4[n]; bp1v[nt] = bp1[n];
  }
#pragma unroll
  for (int mt = 0; mt < 4; ++mt) {
#pragma unroll
    for (int r = 0; r < 4; ++r) {
      float4 o = {0.f, 0.f, 0.f, 0.f};
#pragma unroll
      for (int nt = 0; nt < 4; ++nt) {
        float y = fmaxf(acc[mt][nt][r] + bp1v[nt], 0.f);
        o.x = fmaf(y, wq[nt].x, o.x); o.y = fmaf(y, wq[nt].y, o.y);
        o.z = fmaf(y, wq[nt].z, o.z); o.w = fmaf(y, wq[nt].w, o.w);
      }
#pragma unroll
      for (int off = 1; off <= 8; off <<= 1) {
        o.x += __shfl_xor(o.x, off); o.y += __shfl_xor(o.y, off);
        o.z += __shfl_xor(o.z, off); o.w += __shfl_xor(o.w, off);
      }
      if (c0 == 0) *(float4*)&opart[(wv * 64 + mt * 16 + g * 4 + r) * 4] = o;
    }
  }
  __syncthreads();
  if (t < 64) {
    float4 bp2v = *(const float4*)bp2;
    float4 s0 = *(float4*)&opart[t * 4];
    float4 s1 = *(float4*)&opart[(64 + t) * 4];
    float4 s2 = *(float4*)&opart[(128 + t) * 4];
    float4 s3 = *(float4*)&opart[(192 + t) * 4];
    float4 r;
    r.x = s0.x + s1.x + s2.x + s3.x + bp2v.x;
    r.y = s0.y + s1.y + s2.y + s3.y + bp2v.y;
    r.z = s0.z + s1.z + s2.z + s3.z + bp2v.z;
    r.w = s0.w + s1.w + s2.w + s3.w + bp2v.w;
    out4[m0 + t] = r;
  }
}

extern "C" void kernel_launch(void* const* d_in, const int* in_sizes, int n_in,
                              void* d_out, int out_size, void* d_ws, size_t ws_size,
                              hipStream_t stream) {
  const float* pts   = (const float*)d_in[0];
  const float* w1    = (const float*)d_in[1];
  const float* b1    = (const float*)d_in[2];
  const float* w2    = (const float*)d_in[3];
  const float* b2    = (const float*)d_in[4];
  const float* wsv   = (const float*)d_in[5];
  const float* bs    = (const float*)d_in[6];
  const float* gamma = (const float*)d_in[7];
  const float* beta  = (const float*)d_in[8];
  const float* wp1   = (const float*)d_in[9];
  const float* bp1   = (const float*)d_in[10];
  const float* wp2   = (const float*)d_in[11];
  const float* bp2   = (const float*)d_in[12];

  char* wsb = (char*)d_ws;
  float*    s_raw   = (float*)(wsb + SRAW_OFF);
  float*    stats_f = (float*)(wsb + ST_OFF);
  unsigned* suf     = (unsigned*)(wsb + SUF_OFF);
  ull*      cand    = (ull*)(wsb + CAND_OFF);
  int*      flat_i  = (int*)(wsb + FIDX_OFF);
  float*    sw_raw  = (float*)(wsb + SW_OFF);
  unsigned short* w2h = (unsigned short*)(wsb + W2SH_OFF);
  unsigned short* w2l = (unsigned short*)(wsb + W2SL_OFF);
  unsigned short* p1h = (unsigned short*)(wsb + WP1H_OFF);
  unsigned short* p1l = (unsigned short*)(wsb + WP1L_OFF);

  hipLaunchKernelGGL(k_prep, dim3(17), dim3(256), 0, stream,
                     w2, wp1, w2h, w2l, p1h, p1l, stats_f);
  hipLaunchKernelGGL(k_mlp, dim3(1024), dim3(256), 0, stream,
                     (const float4*)pts, w1, b1, w2h, w2l, b2, wsv, bs,
                     s_raw, stats_f);
  hipLaunchKernelGGL(k_sel, dim3(NB), dim3(1024), 0, stream,
                     s_raw, stats_f, gamma, beta, suf, cand, flat_i, sw_raw);
  hipLaunchKernelGGL(k_proc, dim3(256), dim3(256), 0, stream,
                     (const float4*)pts, w1, b1, w2h, w2l, b2,
                     stats_f, flat_i, sw_raw, p1h, p1l, bp1,
                     (const float4*)wp2, bp2, (float4*)d_out);
}